// Round 8
// baseline (257.747 us; speedup 1.0000x reference)
//
#include <hip/hip_runtime.h>

#define N_TOK  8192
#define KDIM   4096
#define NE     16
#define NSLICE 4                   // k-quarter per block -> 512 blocks, 2/CU
#define TB     64                  // tokens per block (= wave width)
#define BKT    256                 // tile k-width in floats = 1 KB per row
#define NTILE  4                   // 4 tiles x 256 k = 1024 k per block
#define LSTR   260                 // +4 floats -> conflict-free b128 both sides

// Partial logits. Theory after R5/R6/R7: all lane-per-line designs cap at
// ~2.1 TB/s (fabric packet rate: 64 distinct 128 B lines per wave instr);
// the harness fill/copy reach 6.4+ TB/s with contiguous wave bursts. R6 had
// the right pattern (1 KB contiguous single-row reads) but a serial
// stage->barrier->compute loop (duty ~35%). This round: R6's burst pattern +
// register double-buffer (va/vb) so loads for tile t+2 are in flight across
// the whole compute of tile t+1 (16 KB/wave, 128 KB/CU in flight), with no
// vmcnt(0) drain of prefetches (alternating buffers avoid the WAR hazard).
// Compute keeps lane<->token so gate rows are wave-uniform s_loads.
__global__ __launch_bounds__(256, 2)
void router_partial(const float* __restrict__ x, const float* __restrict__ gate,
                    float* __restrict__ ws) {
  __shared__ __align__(16) float tile[TB * LSTR];   // 66.5 KB -> 2 blocks/CU
  const int tid  = threadIdx.x;
  const int lane = tid & 63;
  const int w    = __builtin_amdgcn_readfirstlane(tid >> 6);  // SGPR
  const int g    = blockIdx.x >> 2;          // token group (128)
  const int s    = blockIdx.x & 3;           // k-quarter (4)
  const int t0   = g * TB;

  float acc[NE];
#pragma unroll
  for (int e = 0; e < NE; ++e) acc[e] = 0.f;

  float4 va[16], vb[16];                     // constant-indexed -> SROA, no scratch

// per-block tile rotation: co-resident blocks walk different k-windows
#define KOFF(t) (s * 1024 + ((((t) + g) & 3) * BKT))

// 16 instrs, each 1 KB CONTIGUOUS from ONE row (lane = float4 column)
#define LOADT(dst, t)                                                          \
  {                                                                            \
    _Pragma("unroll")                                                          \
    for (int r = 0; r < 16; ++r) {                                             \
      dst[r] = *(const float4*)(x + (size_t)(t0 + w * 16 + r) * KDIM +         \
                                KOFF(t) + lane * 4);                           \
    }                                                                          \
  }

// banks (65*row + lane) % 32 = distinct per lane -> conflict-free b128
#define WRITET(src)                                                            \
  {                                                                            \
    _Pragma("unroll")                                                          \
    for (int r = 0; r < 16; ++r) {                                             \
      *(float4*)(tile + (w * 16 + r) * LSTR + lane * 4) = src[r];              \
    }                                                                          \
  }

// lane = token, wave w covers k-cols [w*64, w*64+64) of the tile
#define COMPUTET(t)                                                            \
  {                                                                            \
    _Pragma("unroll")                                                          \
    for (int c = 0; c < 16; ++c) {                                             \
      float4 xv4 = *(const float4*)(tile + lane * LSTR + w * 64 + c * 4);      \
      const float xv[4] = {xv4.x, xv4.y, xv4.z, xv4.w};                        \
      const int kk = KOFF(t) + w * 64 + c * 4;                                 \
      _Pragma("unroll")                                                        \
      for (int m = 0; m < 4; ++m) {                                            \
        const float* grow = gate + (size_t)(kk + m) * NE;  /* s_load */        \
        _Pragma("unroll")                                                      \
        for (int e = 0; e < NE; ++e) acc[e] = fmaf(xv[m], grow[e], acc[e]);    \
      }                                                                        \
    }                                                                          \
  }

  LOADT(va, 0)
  WRITET(va)                                 // compiler waits vmcnt for va here
  LOADT(vb, 1)                               // tile1 in flight before barrier
  __syncthreads();
  COMPUTET(0)                                // vb streams in during compute
  __syncthreads();                           // all waves done reading tile0
  WRITET(vb)
  LOADT(va, 2)                               // tile2 in flight through compute1
  __syncthreads();
  COMPUTET(1)
  __syncthreads();
  WRITET(va)
  LOADT(vb, 3)                               // tile3 in flight through compute2
  __syncthreads();
  COMPUTET(2)
  __syncthreads();
  WRITET(vb)
  __syncthreads();
  COMPUTET(3)

  // cross-wave reduction (4 k-strips), one ws float4 per thread
  __syncthreads();                           // compute3 LDS reads done
  float* red = tile;                         // reuse as [256][17]
#pragma unroll
  for (int e = 0; e < NE; ++e) red[(w * 64 + lane) * 17 + e] = acc[e];
  __syncthreads();
  {
    int p0 = tid * 4;                        // 1024 (token,e) pairs, 4/thread
    int t  = p0 >> 4, e0 = p0 & 15;
    float v[4];
#pragma unroll
    for (int j = 0; j < 4; ++j) {
      float sum = 0.f;
#pragma unroll
      for (int ww = 0; ww < 4; ++ww) sum += red[(ww * 64 + t) * 17 + e0 + j];
      v[j] = sum;
    }
    *(float4*)(ws + ((size_t)s * N_TOK + (t0 + t)) * NE + e0) =
        make_float4(v[0], v[1], v[2], v[3]);
  }
}

// Sum 4 slice partials, top-2 (earliest-index tie-break = jax top_k),
// sigmoid, scatter into (E,N) scores; token_indices[e][t] = t (as float).
__global__ __launch_bounds__(256)
void router_finalize(const float* __restrict__ ws, float* __restrict__ out) {
  int t = blockIdx.x * 256 + threadIdx.x;
  float l[NE];
#pragma unroll
  for (int e = 0; e < NE; ++e) l[e] = 0.f;
#pragma unroll
  for (int s = 0; s < NSLICE; ++s) {
    const float4* row = (const float4*)(ws + ((size_t)s * N_TOK + t) * NE);
    float4 r0 = row[0], r1 = row[1], r2 = row[2], r3 = row[3];
    l[0]  += r0.x; l[1]  += r0.y; l[2]  += r0.z; l[3]  += r0.w;
    l[4]  += r1.x; l[5]  += r1.y; l[6]  += r1.z; l[7]  += r1.w;
    l[8]  += r2.x; l[9]  += r2.y; l[10] += r2.z; l[11] += r2.w;
    l[12] += r3.x; l[13] += r3.y; l[14] += r3.z; l[15] += r3.w;
  }
  int i1 = 0; float v1 = l[0];
#pragma unroll
  for (int e = 1; e < NE; ++e) { if (l[e] > v1) { v1 = l[e]; i1 = e; } }
  int i2 = -1; float v2 = -1e30f;
#pragma unroll
  for (int e = 0; e < NE; ++e) { if (e != i1 && l[e] > v2) { v2 = l[e]; i2 = e; } }
  float s1 = 1.f / (1.f + __expf(-v1));
  float s2 = 1.f / (1.f + __expf(-v2));
  float* scores = out;
  float* tix    = out + (size_t)NE * N_TOK;
  float tf = (float)t;
#pragma unroll
  for (int e = 0; e < NE; ++e) {             // coalesced across lanes per e
    scores[(size_t)e * N_TOK + t] = (e == i1) ? s1 : ((e == i2) ? s2 : 0.f);
    tix[(size_t)e * N_TOK + t]    = tf;
  }
}

extern "C" void kernel_launch(void* const* d_in, const int* in_sizes, int n_in,
                              void* d_out, int out_size, void* d_ws, size_t ws_size,
                              hipStream_t stream) {
  const float* x    = (const float*)d_in[0];
  const float* gate = (const float*)d_in[1];
  float* out = (float*)d_out;
  float* ws  = (float*)d_ws;   // needs NSLICE*N_TOK*NE*4 = 2 MB
  router_partial<<<dim3(N_TOK / TB * NSLICE), dim3(256), 0, stream>>>(x, gate, ws);
  router_finalize<<<dim3(N_TOK / 256), dim3(256), 0, stream>>>(ws, out);
}